// Round 4
// baseline (671.299 us; speedup 1.0000x reference)
//
#include <hip/hip_runtime.h>

#define B_ 4
#define C_ 128
#define H_ 256
#define W_ 256

static constexpr int    BC    = B_ * C_;                     // 512 planes
static constexpr size_t PLANE = (size_t)H_ * W_;             // 65536
static constexpr size_t NTOT  = (size_t)B_ * C_ * H_ * W_;   // 33,554,432
static constexpr ptrdiff_t PW = (ptrdiff_t)W_;

typedef float f4 __attribute__((ext_vector_type(4)));

// ---------------------------------------------------------------------------
// SINGLE-VARIABLE A/B vs round 3: all __builtin_nontemporal_store replaced
// with plain stores. Everything else byte-identical. Rationale: kernel sits
// at ~308 us vs a 102-163 us traffic roofline; 80% of ideal traffic is the
// output write stream, all of it nt. The harness fill kernel proves plain
// full-line stores sustain 6.37 TB/s; if nt degrades write-combining, that
// alone explains the ~150 us gap.
//
// grid = 1536 blocks of 256 threads; plane p = bid/3, sub = bid%3:
//   sub 0: vertical block (down + up chains interleaved, thread = column)
//   sub 1: horizontal block rows 0..127   (right + left fused)
//   sub 2: horizontal block rows 128..255 (right + left fused)
// Same-plane blocks adjacent in dispatch -> x read from HBM once, siblings
// hit L2/L3 (they run concurrently, ahead of write-stream eviction).
// ---------------------------------------------------------------------------
__global__ __launch_bounds__(256, 4) void irnn_fused(
    const float* __restrict__ x,
    const float* __restrict__ w_up,    const float* __restrict__ b_up,
    const float* __restrict__ w_right, const float* __restrict__ b_right,
    const float* __restrict__ w_down,  const float* __restrict__ b_down,
    const float* __restrict__ w_left,  const float* __restrict__ b_left,
    float* __restrict__ out_up,   float* __restrict__ out_right,
    float* __restrict__ out_down, float* __restrict__ out_left)
{
    __shared__ float xs[128][67];      // 34,304 B; slots 0..31 right, 33..64 left

    const int bid = blockIdx.x;
    const int p   = bid / 3;                 // plane 0..511
    const int sub = bid - 3 * p;             // 0,1,2
    const int c   = p & (C_ - 1);
    const int tid = threadIdx.x;
    const size_t pbase = (size_t)p * PLANE;

    if (sub == 0) {
        // ================= vertical: down + up in one pass =================
        const float wd = w_down[c], bd = b_down[c];
        const float wu = w_up[c],   bu = b_up[c];
        const float* xb = x + pbase + tid;
        float* od = out_down + pbase + tid;
        float* ou = out_up   + pbase + tid;

        // boundary rows: out = x
        float pd = xb[0];
        float pu = xb[255 * PW];
        od[0]          = pd;
        ou[255 * PW]   = pu;

        const float* xd = xb + PW;           // down input: row 1 ascending
        const float* xu = xb + 254 * PW;     // up   input: row 254 descending
        float* sd = od + PW;
        float* su = ou + 254 * PW;

        float cd[8], cu[8], nd[8], nu[8];
        #pragma unroll
        for (int j = 0; j < 8; ++j) { cd[j] = xd[j * PW]; cu[j] = xu[-j * PW]; }
        xd += 8 * PW; xu -= 8 * PW;

        for (int g = 0; g < 30; ++g) {
            #pragma unroll
            for (int j = 0; j < 8; ++j) { nd[j] = xd[j * PW]; nu[j] = xu[-j * PW]; }
            #pragma unroll
            for (int j = 0; j < 8; ++j) {
                pd = fmaxf(fmaf(wd, pd, bd + cd[j]), 0.f);
                pu = fmaxf(fmaf(wu, pu, bu + cu[j]), 0.f);
                sd[j * PW]  = pd;
                su[-j * PW] = pu;
            }
            sd += 8 * PW; su -= 8 * PW;
            xd += 8 * PW; xu -= 8 * PW;
            #pragma unroll
            for (int j = 0; j < 8; ++j) { cd[j] = nd[j]; cu[j] = nu[j]; }
        }
        // tail: 8 rows from cd/cu (241..248 / 14..7), then 7 (249..255 / 6..0)
        float td[7], tu[7];
        #pragma unroll
        for (int j = 0; j < 7; ++j) { td[j] = xd[j * PW]; tu[j] = xu[-j * PW]; }
        #pragma unroll
        for (int j = 0; j < 8; ++j) {
            pd = fmaxf(fmaf(wd, pd, bd + cd[j]), 0.f);
            pu = fmaxf(fmaf(wu, pu, bu + cu[j]), 0.f);
            sd[j * PW]  = pd;
            su[-j * PW] = pu;
        }
        sd += 8 * PW; su -= 8 * PW;
        #pragma unroll
        for (int j = 0; j < 7; ++j) {
            pd = fmaxf(fmaf(wd, pd, bd + td[j]), 0.f);
            pu = fmaxf(fmaf(wu, pu, bu + tu[j]), 0.f);
            sd[j * PW]  = pd;
            su[-j * PW] = pu;
        }
    } else {
        // ================= horizontal: right + left in one block ===========
        const int r0  = (sub - 1) << 7;      // 0 or 128
        const int d   = tid >> 7;            // 0 = right scanner, 1 = left
        const int rr  = tid & 127;           // scan row within stripe
        const float wc = d ? w_left[c] : w_right[c];
        const float bb = d ? b_left[c] : b_right[c];
        const float* xpl = x + pbase + (size_t)r0 * W_;
        float* o_r = out_right + pbase + (size_t)r0 * W_;
        float* o_l = out_left  + pbase + (size_t)r0 * W_;

        const int q    = tid & 7;            // f4 slot within 32-col chunk
        const int rbas = tid >> 3;           // 0..31

        f4 sreg[8];
        // ---- prologue: load + stage chunk 0 (both directions)
        #pragma unroll
        for (int k = 0; k < 8; ++k) {
            const int df  = k >> 2;                       // 0 right, 1 left
            const int rrr = rbas + ((k & 3) << 5);        // 0..127
            const int cb  = df ? (224 + 4 * q) : (4 * q);
            sreg[k] = *(const f4*)(xpl + (size_t)rrr * W_ + cb);
        }
        #pragma unroll
        for (int k = 0; k < 8; ++k) {
            const int df  = k >> 2;
            const int rrr = rbas + ((k & 3) << 5);
            #pragma unroll
            for (int j = 0; j < 4; ++j) {
                const int sl = df ? (64 - 4 * q - j) : (4 * q + j); // scan order
                xs[rrr][sl] = sreg[k][j];
            }
        }
        __syncthreads();

        float prev = 0.f;
        float* xrow = &xs[rr][d ? 33 : 0];

        for (int ch = 0; ch < 8; ++ch) {
            if (ch < 7) {
                // ---- issue chunk ch+1 global loads (hidden under scan+flush)
                #pragma unroll
                for (int k = 0; k < 8; ++k) {
                    const int df  = k >> 2;
                    const int rrr = rbas + ((k & 3) << 5);
                    const int cb  = df ? (224 - 32 * (ch + 1) + 4 * q)
                                       : (32 * (ch + 1) + 4 * q);
                    sreg[k] = *(const f4*)(xpl + (size_t)rrr * W_ + cb);
                }
            }

            // ---- scan 32 steps in place (thread owns its row+direction)
            float vals[32];
            #pragma unroll
            for (int j = 0; j < 32; ++j) vals[j] = xrow[j];
            #pragma unroll
            for (int j = 0; j < 32; ++j) {
                float v = fmaxf(fmaf(wc, prev, bb + vals[j]), 0.f);
                if (j == 0 && ch == 0) v = vals[0];   // boundary col = input
                xrow[j] = v;
                prev = v;
            }
            __syncthreads();   // scan results visible; all input reads done

            // ---- flush (full-line plain stores) + same-thread restage
            #pragma unroll
            for (int k = 0; k < 8; ++k) {
                const int df  = k >> 2;
                const int rrr = rbas + ((k & 3) << 5);
                f4 v;
                #pragma unroll
                for (int j = 0; j < 4; ++j) {
                    const int sl = df ? (64 - 4 * q - j) : (4 * q + j);
                    v[j] = xs[rrr][sl];
                }
                const int cb = df ? (224 - 32 * ch + 4 * q) : (32 * ch + 4 * q);
                float* dst = (df ? o_l : o_r) + (size_t)rrr * W_ + cb;
                *(f4*)dst = v;
                if (ch < 7) {
                    #pragma unroll
                    for (int j = 0; j < 4; ++j) {
                        const int sl = df ? (64 - 4 * q - j) : (4 * q + j);
                        xs[rrr][sl] = sreg[k][j];     // same slots this thread
                    }                                 // just flushed -> no race
                }
            }
            __syncthreads();   // staged chunk visible to scanners
        }
    }
}

// ---------------------------------------------------------------------------
extern "C" void kernel_launch(void* const* d_in, const int* in_sizes, int n_in,
                              void* d_out, int out_size, void* d_ws, size_t ws_size,
                              hipStream_t stream) {
    // setup_inputs() dict order: input, w_up, b_up, w_right, b_right,
    //                            w_down, b_down, w_left, b_left
    const float* x       = (const float*)d_in[0];
    const float* w_up    = (const float*)d_in[1];
    const float* b_up    = (const float*)d_in[2];
    const float* w_right = (const float*)d_in[3];
    const float* b_right = (const float*)d_in[4];
    const float* w_down  = (const float*)d_in[5];
    const float* b_down  = (const float*)d_in[6];
    const float* w_left  = (const float*)d_in[7];
    const float* b_left  = (const float*)d_in[8];

    float* out       = (float*)d_out;       // [up | right | down | left]
    float* out_up    = out;
    float* out_right = out + NTOT;
    float* out_down  = out + 2 * NTOT;
    float* out_left  = out + 3 * NTOT;

    irnn_fused<<<dim3(3 * BC), dim3(256), 0, stream>>>(
        x, w_up, b_up, w_right, b_right, w_down, b_down, w_left, b_left,
        out_up, out_right, out_down, out_left);
}